// Round 5
// baseline (558.130 us; speedup 1.0000x reference)
//
#include <hip/hip_runtime.h>

#define VERTS   100000
#define NCLUST  25000
#define BATCH_N 1024
#define THREADS 1024
#define NREP    2   // DIAGNOSTIC: run the gather phase twice (idempotent) so the
                    // dispatch (~440us) outlasts the ~258us poison fills and
                    // finally surfaces in the rocprof top-5 with full counters.

typedef float  f32x4 __attribute__((ext_vector_type(4)));
typedef int    i32x4 __attribute__((ext_vector_type(4)));

// out[b, v] = x[b, v2c[v]]
// Exact R0 structure (twice-verified at 479/480us) except phase 2 repeats
// NREP times writing identical values — a pure measurement build to capture
// FETCH/WRITE/hbm_gbps/BANK_CONFLICT/VALUBusy for the gather itself.
__global__ __launch_bounds__(THREADS) void gather_lds_diag_kernel(
    const float* __restrict__ x,     // [BATCH_N, NCLUST]
    const int*   __restrict__ v2c,   // [VERTS]
    float*       __restrict__ out)   // [BATCH_N, VERTS]
{
    extern __shared__ float lds[];   // NCLUST floats = 100000 bytes
    const int b   = blockIdx.x;
    const int tid = threadIdx.x;

    // Phase 1: coalesced float4 staging of the whole row into LDS.
    const f32x4* __restrict__ xrow4 =
        reinterpret_cast<const f32x4*>(x + (size_t)b * NCLUST);
    f32x4* lds4 = reinterpret_cast<f32x4*>(lds);
    for (int i = tid; i < NCLUST / 4; i += THREADS) {
        lds4[i] = __builtin_nontemporal_load(&xrow4[i]);
    }
    __syncthreads();

    // Phase 2 (x NREP): int4 idx load, 4 LDS gathers, float4 streaming store.
    const i32x4* __restrict__ v2c4 = reinterpret_cast<const i32x4*>(v2c);
    f32x4* __restrict__ out4 =
        reinterpret_cast<f32x4*>(out + (size_t)b * VERTS);
    for (int rep = 0; rep < NREP; ++rep) {
        for (int q = tid; q < VERTS / 4; q += THREADS) {
            const i32x4 idx = v2c4[q];
            f32x4 o;
            o.x = lds[idx.x];
            o.y = lds[idx.y];
            o.z = lds[idx.z];
            o.w = lds[idx.w];
            __builtin_nontemporal_store(o, &out4[q]);
        }
    }
}

extern "C" void kernel_launch(void* const* d_in, const int* in_sizes, int n_in,
                              void* d_out, int out_size, void* d_ws, size_t ws_size,
                              hipStream_t stream) {
    const float* x   = (const float*)d_in[0];   // [1024, 25000] f32
    const int*   v2c = (const int*)d_in[1];     // [100000] i32
    float*       out = (float*)d_out;           // [1024, 100000] f32

    const int lds_bytes = NCLUST * (int)sizeof(float);  // 100000 B > 64 KB default cap
    static bool attr_set = false;  // idempotent host-side attribute, not a stream op
    if (!attr_set) {
        hipFuncSetAttribute(reinterpret_cast<const void*>(gather_lds_diag_kernel),
                            hipFuncAttributeMaxDynamicSharedMemorySize, lds_bytes);
        attr_set = true;
    }

    gather_lds_diag_kernel<<<BATCH_N, THREADS, lds_bytes, stream>>>(x, v2c, out);
}